// Round 1
// baseline (81.584 us; speedup 1.0000x reference)
//
#include <hip/hip_runtime.h>

// UnionLayer: out[b, n]      = -1/(-1 + sum_d ln(1 - (1-x[b,d])*W_con[n,d]))   n in [0,256)
//             out[b, 256+n]  = 1 - (-1/(-1 + sum_d ln(1 - x[b,d]*W_dis[n,d])))
// B=1024, D=512, N=256 -> out (1024, 512) f32.
//
// Trick: sum of logs -> log of 32-term partial products (terms in (0.5,1], so
// product >= 2^-32, no underflow). Inner loop is fma+mul only; one v_log_f32
// per output per 32 d's.

#define DDIM 512
#define NTOT 512
#define NHALF 256
#define BM 64
#define BN 32
#define BK 32
#define BKP 36   // padded LDS row stride (floats); 36*4=144B, 16B-aligned rows

__global__ __launch_bounds__(256) void union_kernel(
    const float* __restrict__ x,
    const float* __restrict__ Wc,
    const float* __restrict__ Wd,
    float* __restrict__ out)
{
    __shared__ float xs[BM * BKP];
    __shared__ float ws[BN * BKP];

    const int tid   = threadIdx.x;
    const int ntile = blockIdx.x;          // 0..15 over 512 output cols
    const int btile = blockIdx.y;          // 0..15 over 1024 rows
    const int n0    = ntile * BN;
    const int b0    = btile * BM;
    const bool isCon = (n0 < NHALF);

    // u = 1-x (con) or x (dis): u = csel*x + coff
    const float csel = isCon ? -1.0f : 1.0f;
    const float coff = isCon ?  1.0f : 0.0f;
    const float* Wbase = isCon ? (Wc + n0 * DDIM) : (Wd + (n0 - NHALF) * DDIM);

    // staging map: 8 threads per row, float4 along d
    const int srow = tid >> 3;             // 0..31
    const int sc4  = (tid & 7) * 4;        // 0,4,...,28

    // compute map: 16x16 thread grid, each thread 4 b-rows x 2 n-cols
    const int tb = tid >> 4;               // 0..15
    const int tn = tid & 15;               // 0..15

    float4 xr0, xr1, wr0;
    auto load_tile = [&](int d0) {
        xr0 = *reinterpret_cast<const float4*>(&x[(b0 + srow) * DDIM + d0 + sc4]);
        xr1 = *reinterpret_cast<const float4*>(&x[(b0 + srow + 32) * DDIM + d0 + sc4]);
        wr0 = *reinterpret_cast<const float4*>(&Wbase[srow * DDIM + d0 + sc4]);
    };

    float prod[4][2], acc[4][2];
#pragma unroll
    for (int i = 0; i < 4; ++i)
#pragma unroll
        for (int j = 0; j < 2; ++j) { prod[i][j] = 1.0f; acc[i][j] = 0.0f; }

    load_tile(0);

    constexpr int NT = DDIM / BK;          // 16 k-tiles
#pragma unroll 1
    for (int t = 0; t < NT; ++t) {
        // write staged regs to LDS (u-transform applied to x)
        float4 u0, u1;
        u0.x = fmaf(csel, xr0.x, coff); u0.y = fmaf(csel, xr0.y, coff);
        u0.z = fmaf(csel, xr0.z, coff); u0.w = fmaf(csel, xr0.w, coff);
        u1.x = fmaf(csel, xr1.x, coff); u1.y = fmaf(csel, xr1.y, coff);
        u1.z = fmaf(csel, xr1.z, coff); u1.w = fmaf(csel, xr1.w, coff);
        *reinterpret_cast<float4*>(&xs[srow * BKP + sc4])        = u0;
        *reinterpret_cast<float4*>(&xs[(srow + 32) * BKP + sc4]) = u1;
        *reinterpret_cast<float4*>(&ws[srow * BKP + sc4])        = wr0;
        __syncthreads();

        if (t + 1 < NT) load_tile((t + 1) * BK);   // overlap with compute

#pragma unroll
        for (int k4 = 0; k4 < BK; k4 += 4) {
            float4 uu[4], wv[2];
#pragma unroll
            for (int i = 0; i < 4; ++i)
                uu[i] = *reinterpret_cast<const float4*>(&xs[(tb * 4 + i) * BKP + k4]);
#pragma unroll
            for (int j = 0; j < 2; ++j)
                wv[j] = *reinterpret_cast<const float4*>(&ws[(tn * 2 + j) * BKP + k4]);
#pragma unroll
            for (int i = 0; i < 4; ++i)
#pragma unroll
                for (int j = 0; j < 2; ++j) {
                    prod[i][j] *= fmaf(-uu[i].x, wv[j].x, 1.0f);
                    prod[i][j] *= fmaf(-uu[i].y, wv[j].y, 1.0f);
                    prod[i][j] *= fmaf(-uu[i].z, wv[j].z, 1.0f);
                    prod[i][j] *= fmaf(-uu[i].w, wv[j].w, 1.0f);
                }
        }

        // fold this tile's partial product into the log-accumulator
#pragma unroll
        for (int i = 0; i < 4; ++i)
#pragma unroll
            for (int j = 0; j < 2; ++j) {
                acc[i][j] += __log2f(prod[i][j]);
                prod[i][j] = 1.0f;
            }
        __syncthreads();
    }

    constexpr float LN2 = 0.69314718055994530942f;
#pragma unroll
    for (int i = 0; i < 4; ++i) {
        const int b = b0 + tb * 4 + i;
        float2 v;
        {
            const float S0 = acc[i][0] * LN2;
            const float r0 = 1.0f / (1.0f - S0);
            v.x = isCon ? r0 : 1.0f - r0;
        }
        {
            const float S1 = acc[i][1] * LN2;
            const float r1 = 1.0f / (1.0f - S1);
            v.y = isCon ? r1 : 1.0f - r1;
        }
        *reinterpret_cast<float2*>(&out[b * NTOT + n0 + tn * 2]) = v;
    }
}

extern "C" void kernel_launch(void* const* d_in, const int* in_sizes, int n_in,
                              void* d_out, int out_size, void* d_ws, size_t ws_size,
                              hipStream_t stream) {
    const float* x  = (const float*)d_in[0];
    const float* Wc = (const float*)d_in[1];
    const float* Wd = (const float*)d_in[2];
    float* out = (float*)d_out;
    dim3 grid(NTOT / BN, 1024 / BM);   // (16, 16)
    union_kernel<<<grid, 256, 0, stream>>>(x, Wc, Wd, out);
}